// Round 3
// baseline (169.720 us; speedup 1.0000x reference)
//
#include <hip/hip_runtime.h>
#include <math.h>

// EKF propagate: B=65536, nx=16, nz=8, nu=4, fp32.
//
// R7 vs R6 (61.0us/dispatch, VALUBusy 42%): R4/R5/R6 all land at 61-65us
// despite +/-35% VALU swings -> shared stall floor. Diagnosis: the V/W/tp
// loops stream uniform A/C via s_load while interleaving ds_write/ds_read.
// SMEM shares lgkmcnt with DS and completes OUT OF ORDER, so every use of
// s_load data with DS in flight forces s_waitcnt lgkmcnt(0) full drains:
// ~16+16+8 serialized ~100cy joins per wave that wave-count restructuring
// cannot touch (lockstep waves stall together).
// Fix: stage A (1KB) + C (512B) into block LDS once (one __syncthreads),
// and read them as uniform-address ds_read_b128 broadcasts -- DS is
// IN-ORDER, so the compiler pipelines with counted lgkmcnt(N) waits and
// the interleaved VT/TPT ds_writes share the same in-order stream.
// LDS 39424 -> 40960 B = exactly 4 blocks/CU (occupancy unchanged).
// Everything else identical to R6 (isolates the SMEM variable).

namespace {

constexpr int LPE    = 8;            // lanes per element
constexpr int GROUPS = 32;           // elements per block
constexpr int TPB    = GROUPS * LPE; // 256 threads

// Per-group LDS layout (floats). Overlays by liveness:
//  [0,256)   VT : VTs[j][r] = V[r][j], 16 rows x 16   [V .. W]
//  [0,128)   TPT: TPT[m][r] = tp[r][m], 8 rows x 16   [tp .. final] (overlay)
//  [128,192) SI : S^-1 rows 8x8                       [post-GJ .. K]
//  [256,272) mubar[16]; [272,288) d[16]; [288,296) h[8]; [296,304) dh[8]
constexpr int O_VT  = 0;
constexpr int O_TPT = 0;
constexpr int O_SI  = 128;
constexpr int O_MU  = 256;
constexpr int O_D   = 272;
constexpr int O_H   = 288;
constexpr int O_DH  = 296;
constexpr int GS    = 308;  // %32==20, %4==0: per-wave group bases on
                            // distinct banks; float4-aligned
// Block-shared staging of the uniform matrices (read via ds broadcast):
constexpr int O_A   = GS * GROUPS;   // 9856: A copy, 256 floats
constexpr int O_C   = O_A + 256;     // C copy, 128 floats
constexpr int LDS_FLOATS = O_C + 128; // 10240 floats = 40960 B (4 blocks/CU)

__device__ __forceinline__ float dot4(float4 a, float4 b) {
  return a.x*b.x + a.y*b.y + a.z*b.z + a.w*b.w;
}

// s[16] (scalar regs) dot (a0,a1,a2,a3) quads
#define DOT16(s, a0,a1,a2,a3) ( s[0]*a0.x + s[1]*a0.y + s[2]*a0.z + s[3]*a0.w \
  + s[4]*a1.x + s[5]*a1.y + s[6]*a1.z + s[7]*a1.w \
  + s[8]*a2.x + s[9]*a2.y + s[10]*a2.z + s[11]*a2.w \
  + s[12]*a3.x + s[13]*a3.y + s[14]*a3.z + s[15]*a3.w )

// tanh(x) = 1 - 2/(e^{2x}+1); v_exp_f32 + v_rcp_f32. abs err ~1e-7.
__device__ __forceinline__ float tanh_fast(float x) {
  float e = __expf(2.0f * x);
  return 1.0f - 2.0f * __builtin_amdgcn_rcpf(e + 1.0f);
}

// ds_swizzle BitMode: src_lane = ((lane & 0x18) | P) -> broadcast lane P of
// each 8-lane group (offset imm must be a literal -> macro, not function).
#define SWZF(v, imm) __int_as_float(__builtin_amdgcn_ds_swizzle(__float_as_int(v), (imm)))

// One Gauss-Jordan elimination step for pivot P (P is a literal).
// Rows live in registers: s8[8] (S row t), x8[8] (inverse row t).
// Invariants at entry to step P:
//   - s8[j] maintained for j >= P;  x8[j] maintained for j < P; x8[j>=P]=delta_tj
//   - pivot row's x8[P] == 1 (so px[P]*rp == rp, no swizzle needed)
// f-trick: for t==P, f = ps[P]-1 makes  s8[j] - f*(ps[j]*rp) == ps[j]*rp
// (the normalized pivot row) -- branchless unification, 1 cndmask per step.
#define GJ_STEP(P)                                                         \
  {                                                                        \
    float ps[8], px[8];                                                    \
    _Pragma("unroll")                                                      \
    for (int j = 0; j < 8; j++) {                                          \
      if (j >= (P)) ps[j] = SWZF(s8[j], (((P) << 5) | 0x18));              \
      else          px[j] = SWZF(x8[j], (((P) << 5) | 0x18));              \
    }                                                                      \
    const float rp = __builtin_amdgcn_rcpf(ps[(P)]);                       \
    const float f  = (t == (P)) ? (ps[(P)] - 1.0f) : s8[(P)];              \
    _Pragma("unroll")                                                      \
    for (int j = 0; j < 8; j++) {                                          \
      if (j > (P))      s8[j] -= f * (ps[j] * rp);                         \
      else if (j < (P)) x8[j] -= f * (px[j] * rp);                         \
    }                                                                      \
    x8[(P)] -= f * rp;                                                     \
  }

__global__ __launch_bounds__(TPB)
void ekf_kernel(const float* __restrict__ mu_prev,
                const float* __restrict__ Sig_prev,
                const float* __restrict__ U,
                const float* __restrict__ Z,
                const float* __restrict__ A,
                const float* __restrict__ Bm,
                const float* __restrict__ C,
                const float* __restrict__ Q,
                const float* __restrict__ R,
                float* __restrict__ mu_out,
                float* __restrict__ sig_out,
                int Btot)
{
  __shared__ float lds[LDS_FLOATS];    // 40960 B -> exactly 4 blocks/CU
  const int tid = threadIdx.x;
  const int g = tid >> 3;              // group (element) within block
  const int t = tid & 7;               // lane within group
  int e = blockIdx.x * GROUPS + g;
  if (e >= Btot) e = Btot - 1;         // clamp; duplicate-write benign
  float* L = lds + g * GS;
  const int r0 = t, r1 = t + 8;        // owned matrix rows

  // ---- stage A (64 f4) + C (32 f4) into block LDS (first memory op) ----
  if (tid < 96) {
    float4 v = (tid < 64) ? ((const float4*)A)[tid]
                          : ((const float4*)C)[tid - 64];
    ((float4*)(lds + O_A))[tid] = v;
  }

  // ---- load Sigma rows r0, r1 ----
  float sig0[16], sig1[16];
  {
    const float4* s0 = (const float4*)(Sig_prev + (size_t)e * 256 + r0 * 16);
    const float4* s1 = (const float4*)(Sig_prev + (size_t)e * 256 + r1 * 16);
    #pragma unroll
    for (int c = 0; c < 4; c++) {
      float4 v0 = s0[c], v1 = s1[c];
      sig0[4*c+0]=v0.x; sig0[4*c+1]=v0.y; sig0[4*c+2]=v0.z; sig0[4*c+3]=v0.w;
      sig1[4*c+0]=v1.x; sig1[4*c+1]=v1.y; sig1[4*c+2]=v1.z; sig1[4*c+3]=v1.w;
    }
  }

  // ---- mu_bar rows r0,r1 (dual chains; per-lane A rows stay global/L1) ----
  float mubar0, mubar1, d0loc, d1loc;
  {
    const float4* mr = (const float4*)(mu_prev + (size_t)e * 16);
    float4 m0 = mr[0], m1 = mr[1], m2 = mr[2], m3 = mr[3];
    const float4* a0 = (const float4*)(A + r0 * 16);
    const float4* a1 = (const float4*)(A + r1 * 16);
    float p0 = dot4(a0[0],m0)+dot4(a0[1],m1)+dot4(a0[2],m2)+dot4(a0[3],m3);
    float p1 = dot4(a1[0],m0)+dot4(a1[1],m1)+dot4(a1[2],m2)+dot4(a1[3],m3);
    float4 u4 = *(const float4*)(U + (size_t)e * 4);
    p0 += dot4(*(const float4*)(Bm + r0 * 4), u4);
    p1 += dot4(*(const float4*)(Bm + r1 * 4), u4);
    mubar0 = tanh_fast(p0); d0loc = 1.0f - mubar0 * mubar0;
    mubar1 = tanh_fast(p1); d1loc = 1.0f - mubar1 * mubar1;
  }

  __syncthreads();                     // staged A/C visible to all waves

  L[O_MU + r0] = mubar0; L[O_MU + r1] = mubar1;
  L[O_D  + r0] = d0loc;  L[O_D  + r1] = d1loc;
  __builtin_amdgcn_wave_barrier();

  // ---- h[t], dh[t]; keep C row t in regs for S-build ----
  float4 ct0, ct1, ct2, ct3;
  float dhl;
  {
    const float4* cr = (const float4*)(lds + O_C + t * 16);  // DS broadcast-ish
    ct0 = cr[0]; ct1 = cr[1]; ct2 = cr[2]; ct3 = cr[3];
    const float4* mb = (const float4*)(L + O_MU);
    float ph = dot4(ct0,mb[0])+dot4(ct1,mb[1])+dot4(ct2,mb[2])+dot4(ct3,mb[3]);
    float hb = tanh_fast(ph); dhl = 1.0f - hb * hb;
    L[O_H + t] = hb; L[O_DH + t] = dhl;
  }
  __builtin_amdgcn_wave_barrier();
  float dh[8];
  {
    float4 v0 = *(const float4*)(L + O_DH);
    float4 v1 = *(const float4*)(L + O_DH + 4);
    dh[0]=v0.x; dh[1]=v0.y; dh[2]=v0.z; dh[3]=v0.w;
    dh[4]=v1.x; dh[5]=v1.y; dh[6]=v1.z; dh[7]=v1.w;
  }

  // ---- V = Sig * A^T rows r0,r1; A rows via in-order DS broadcasts ----
  #pragma unroll
  for (int j = 0; j < 16; j++) {
    const float4* a4 = (const float4*)(lds + O_A + j * 16);
    float4 a0 = a4[0], a1 = a4[1], a2 = a4[2], a3 = a4[3];
    float acc0 = DOT16(sig0, a0, a1, a2, a3);
    float acc1 = DOT16(sig1, a0, a1, a2, a3);
    L[O_VT + j*16 + r0] = acc0;               // b32 writes: same DS stream
    L[O_VT + j*16 + r1] = acc1;
  }
  __builtin_amdgcn_wave_barrier();

  // ---- W rows r0,r1 (W = A*V, symmetric: col c == row c) ----
  float sb0[16], sb1[16];
  {
    float v0[16], v1[16];
    const float4* p0 = (const float4*)(L + O_VT + r0 * 16);
    const float4* p1 = (const float4*)(L + O_VT + r1 * 16);
    #pragma unroll
    for (int c = 0; c < 4; c++) {
      float4 x0 = p0[c], x1 = p1[c];
      v0[4*c+0]=x0.x; v0[4*c+1]=x0.y; v0[4*c+2]=x0.z; v0[4*c+3]=x0.w;
      v1[4*c+0]=x1.x; v1[4*c+1]=x1.y; v1[4*c+2]=x1.z; v1[4*c+3]=x1.w;
    }
    #pragma unroll
    for (int i = 0; i < 16; i++) {
      const float4* a4 = (const float4*)(lds + O_A + i * 16);
      float4 a0 = a4[0], a1 = a4[1], a2 = a4[2], a3 = a4[3];
      sb0[i] = DOT16(v0, a0, a1, a2, a3);
      sb1[i] = DOT16(v1, a0, a1, a2, a3);
    }
  }
  __builtin_amdgcn_wave_barrier();            // VT dead; TPT may overlay

  // ---- Sig_bar rows: sb_r = R[r,:] + d_r * W[r,:] * d ----
  {
    const float4* rr0 = (const float4*)(R + r0 * 16);
    const float4* rr1 = (const float4*)(R + r1 * 16);
    const float4* dv  = (const float4*)(L + O_D);
    #pragma unroll
    for (int c = 0; c < 4; c++) {
      float4 ra = rr0[c], rb = rr1[c], dd = dv[c];
      sb0[4*c+0] = ra.x + d0loc*sb0[4*c+0]*dd.x;
      sb0[4*c+1] = ra.y + d0loc*sb0[4*c+1]*dd.y;
      sb0[4*c+2] = ra.z + d0loc*sb0[4*c+2]*dd.z;
      sb0[4*c+3] = ra.w + d0loc*sb0[4*c+3]*dd.w;
      sb1[4*c+0] = rb.x + d1loc*sb1[4*c+0]*dd.x;
      sb1[4*c+1] = rb.y + d1loc*sb1[4*c+1]*dd.y;
      sb1[4*c+2] = rb.z + d1loc*sb1[4*c+2]*dd.z;
      sb1[4*c+3] = rb.w + d1loc*sb1[4*c+3]*dd.w;
    }
  }

  // ---- tp rows r0,r1 = Sig_bar[r,:] C^T Dh ; C rows via DS broadcasts ----
  float tp0[8], tp1[8];
  #pragma unroll
  for (int m = 0; m < 8; m++) {
    const float4* c4 = (const float4*)(lds + O_C + m * 16);
    float4 c0 = c4[0], c1 = c4[1], c2 = c4[2], c3 = c4[3];
    tp0[m] = DOT16(sb0, c0, c1, c2, c3) * dh[m];
    tp1[m] = DOT16(sb1, c0, c1, c2, c3) * dh[m];
    L[O_TPT + m*16 + r0] = tp0[m];
    L[O_TPT + m*16 + r1] = tp1[m];
  }
  __builtin_amdgcn_wave_barrier();

  // ---- S row t = dh_t * (C[t,:] @ tp) + Q[t,:]  (C row t in regs) ----
  float s8[8];
  {
    float4 q0 = *(const float4*)(Q + t * 8);
    float4 q1 = *(const float4*)(Q + t * 8 + 4);
    float qv[8] = {q0.x,q0.y,q0.z,q0.w,q1.x,q1.y,q1.z,q1.w};
    #pragma unroll
    for (int m = 0; m < 8; m++) {
      const float4* tr = (const float4*)(L + O_TPT + m * 16);  // broadcast
      float acc = dot4(ct0,tr[0]) + dot4(ct1,tr[1])
                + dot4(ct2,tr[2]) + dot4(ct3,tr[3]);
      s8[m] = acc * dhl + qv[m];
    }
  }

  // ---- Gauss-Jordan inverse of S via swizzle broadcasts (no LDS, no
  //      barriers, all lanes active; S SPD -> no pivoting) ----
  float x8[8];
  #pragma unroll
  for (int j = 0; j < 8; j++) x8[j] = (j == t) ? 1.0f : 0.0f;
  GJ_STEP(0) GJ_STEP(1) GJ_STEP(2) GJ_STEP(3)
  GJ_STEP(4) GJ_STEP(5) GJ_STEP(6) GJ_STEP(7)

  // ---- stash S^-1 rows ----
  *((float4*)(L + O_SI + t*8 + 0)) = make_float4(x8[0], x8[1], x8[2], x8[3]);
  *((float4*)(L + O_SI + t*8 + 4)) = make_float4(x8[4], x8[5], x8[6], x8[7]);
  __builtin_amdgcn_wave_barrier();

  // ---- K rows r0,r1 = tp[r,:] @ Sinv ----
  float k0[8] = {0,0,0,0,0,0,0,0};
  float k1[8] = {0,0,0,0,0,0,0,0};
  #pragma unroll
  for (int m = 0; m < 8; m++) {
    float4 a = *(const float4*)(L + O_SI + m*8 + 0);   // broadcast
    float4 b = *(const float4*)(L + O_SI + m*8 + 4);
    float f0 = tp0[m], f1 = tp1[m];
    k0[0]+=f0*a.x; k0[1]+=f0*a.y; k0[2]+=f0*a.z; k0[3]+=f0*a.w;
    k0[4]+=f0*b.x; k0[5]+=f0*b.y; k0[6]+=f0*b.z; k0[7]+=f0*b.w;
    k1[0]+=f1*a.x; k1[1]+=f1*a.y; k1[2]+=f1*a.z; k1[3]+=f1*a.w;
    k1[4]+=f1*b.x; k1[5]+=f1*b.y; k1[6]+=f1*b.z; k1[7]+=f1*b.w;
  }

  // ---- mu rows r0,r1 ----
  {
    float4 z0 = *(const float4*)(Z + (size_t)e * 8);
    float4 z1 = *(const float4*)(Z + (size_t)e * 8 + 4);
    float4 h0 = *(const float4*)(L + O_H);
    float4 h1 = *(const float4*)(L + O_H + 4);
    float i0=z0.x-h0.x, i1=z0.y-h0.y, i2=z0.z-h0.z, i3=z0.w-h0.w;
    float i4=z1.x-h1.x, i5=z1.y-h1.y, i6=z1.z-h1.z, i7=z1.w-h1.w;
    float mu0 = mubar0 + k0[0]*i0+k0[1]*i1+k0[2]*i2+k0[3]*i3
                       + k0[4]*i4+k0[5]*i5+k0[6]*i6+k0[7]*i7;
    float mu1 = mubar1 + k1[0]*i0+k1[1]*i1+k1[2]*i2+k1[3]*i3
                       + k1[4]*i4+k1[5]*i5+k1[6]*i6+k1[7]*i7;
    mu_out[(size_t)e * 16 + r0] = mu0;
    mu_out[(size_t)e * 16 + r1] = mu1;
  }

  // ---- Sig_now rows = Sig_bar - K tp^T  (K S = tp exactly in real
  //      arithmetic -> equals Joseph form; fp delta ~1e-6) ----
  #pragma unroll
  for (int m = 0; m < 8; m++) {
    const float4* tr = (const float4*)(L + O_TPT + m * 16);  // broadcast
    float4 t0 = tr[0], t1 = tr[1], t2 = tr[2], t3 = tr[3];
    float km0 = k0[m], km1 = k1[m];
    sb0[0] -=km0*t0.x; sb0[1] -=km0*t0.y; sb0[2] -=km0*t0.z; sb0[3] -=km0*t0.w;
    sb0[4] -=km0*t1.x; sb0[5] -=km0*t1.y; sb0[6] -=km0*t1.z; sb0[7] -=km0*t1.w;
    sb0[8] -=km0*t2.x; sb0[9] -=km0*t2.y; sb0[10]-=km0*t2.z; sb0[11]-=km0*t2.w;
    sb0[12]-=km0*t3.x; sb0[13]-=km0*t3.y; sb0[14]-=km0*t3.z; sb0[15]-=km0*t3.w;
    sb1[0] -=km1*t0.x; sb1[1] -=km1*t0.y; sb1[2] -=km1*t0.z; sb1[3] -=km1*t0.w;
    sb1[4] -=km1*t1.x; sb1[5] -=km1*t1.y; sb1[6] -=km1*t1.z; sb1[7] -=km1*t1.w;
    sb1[8] -=km1*t2.x; sb1[9] -=km1*t2.y; sb1[10]-=km1*t2.z; sb1[11]-=km1*t2.w;
    sb1[12]-=km1*t3.x; sb1[13]-=km1*t3.y; sb1[14]-=km1*t3.z; sb1[15]-=km1*t3.w;
  }
  {
    float4* o0 = (float4*)(sig_out + (size_t)e * 256 + r0 * 16);
    float4* o1 = (float4*)(sig_out + (size_t)e * 256 + r1 * 16);
    o0[0] = make_float4(sb0[0],  sb0[1],  sb0[2],  sb0[3]);
    o0[1] = make_float4(sb0[4],  sb0[5],  sb0[6],  sb0[7]);
    o0[2] = make_float4(sb0[8],  sb0[9],  sb0[10], sb0[11]);
    o0[3] = make_float4(sb0[12], sb0[13], sb0[14], sb0[15]);
    o1[0] = make_float4(sb1[0],  sb1[1],  sb1[2],  sb1[3]);
    o1[1] = make_float4(sb1[4],  sb1[5],  sb1[6],  sb1[7]);
    o1[2] = make_float4(sb1[8],  sb1[9],  sb1[10], sb1[11]);
    o1[3] = make_float4(sb1[12], sb1[13], sb1[14], sb1[15]);
  }
}

} // namespace

extern "C" void kernel_launch(void* const* d_in, const int* in_sizes, int n_in,
                              void* d_out, int out_size, void* d_ws, size_t ws_size,
                              hipStream_t stream)
{
  const float* mu_prev = (const float*)d_in[0];
  const float* Sigma   = (const float*)d_in[1];
  const float* u       = (const float*)d_in[2];
  const float* z       = (const float*)d_in[3];
  const float* A       = (const float*)d_in[4];
  const float* Bm      = (const float*)d_in[5];
  const float* C       = (const float*)d_in[6];
  const float* Q       = (const float*)d_in[7];
  const float* R       = (const float*)d_in[8];

  const int Btot = in_sizes[0] / 16;                 // B = 65536
  float* mu_out  = (float*)d_out;
  float* sig_out = (float*)d_out + (size_t)Btot * 16;

  const int grid = (Btot + GROUPS - 1) / GROUPS;     // 2048 blocks x 256 thr
  ekf_kernel<<<grid, TPB, 0, stream>>>(mu_prev, Sigma, u, z, A, Bm, C, Q, R,
                                       mu_out, sig_out, Btot);
}